// Round 1
// baseline (534.168 us; speedup 1.0000x reference)
//
#include <hip/hip_runtime.h>
#include <hip/hip_bf16.h>

// Fused MHA forward for MI355X (gfx950).
// B=2, S=2048, E=2048, H=16, D=128.
// Pipeline: cvt(x)->bf16 ; transcvt(W)->bf16 [N,K] ; GEMM1(qkv,+bias, scatter to
// [B,H,S,D]) ; flash-attn ; GEMM2(+bias)->fp32 out.
// All MFMA = v_mfma_f32_16x16x32_bf16, fp32 accum.
// ws layout (bytes):           offset        size
//   xb    [4096][2048] bf16           0   16,777,216
//   wqkvT [6144][2048] bf16  16,777,216   25,165,824
//   wprojT[2048][2048] bf16  41,943,040    8,388,608
//   q     [32][2048][128]    50,331,648   16,777,216
//   k                        67,108,864   16,777,216
//   v                        83,886,080   16,777,216
//   attb  [4096][2048] bf16 100,663,296   16,777,216  -> total 117,440,512 B

typedef __bf16 bf16x8 __attribute__((ext_vector_type(8)));
typedef __bf16 bf16x4 __attribute__((ext_vector_type(4)));
typedef float  f32x4  __attribute__((ext_vector_type(4)));

static __device__ __forceinline__ bf16x8 ld8(const __bf16* p){
  return *reinterpret_cast<const bf16x8*>(p);
}

// ---------------- fp32 -> bf16 elementwise ----------------
__global__ __launch_bounds__(256) void cvt_kernel(const float* __restrict__ src,
                                                  __bf16* __restrict__ dst, int n4){
  int stride = gridDim.x * blockDim.x;
  for (int i = blockIdx.x*blockDim.x + threadIdx.x; i < n4; i += stride){
    float4 v = reinterpret_cast<const float4*>(src)[i];
    bf16x4 o;
    o[0] = (__bf16)v.x; o[1] = (__bf16)v.y; o[2] = (__bf16)v.z; o[3] = (__bf16)v.w;
    reinterpret_cast<bf16x4*>(dst)[i] = o;
  }
}

// ---------------- fp32 [K][N] -> bf16 [N][K] (transpose + cast) ----------------
__global__ __launch_bounds__(256) void transcvt_kernel(const float* __restrict__ src,
                                                       __bf16* __restrict__ dst,
                                                       int K, int N){
  __shared__ float tile[32][33];
  const int n0 = blockIdx.x*32, k0 = blockIdx.y*32;
  const int tx = threadIdx.x & 31, ty = threadIdx.x >> 5;
  #pragma unroll
  for (int i = 0; i < 32; i += 8)
    tile[ty+i][tx] = src[(size_t)(k0+ty+i)*N + n0 + tx];
  __syncthreads();
  #pragma unroll
  for (int i = 0; i < 32; i += 8)
    dst[(size_t)(n0+ty+i)*K + k0 + tx] = (__bf16)tile[tx][ty+i];
}

// ---------------- bf16 GEMM: C[M,N] = A[M,K] * Bt[N,K]^T + bias ----------------
// 128x128 block tile, 4 waves (2x2), each wave 64x64 = 4x4 MFMA frags, BK=32.
// EPI 0: scatter bf16 into q/k/v [B,H,S,D];  EPI 1: fp32 C + bias.
template<int EPI>
__global__ __launch_bounds__(256) void gemm_bt(const __bf16* __restrict__ A,
    const __bf16* __restrict__ Bt, const float* __restrict__ bias,
    __bf16* __restrict__ outb, float* __restrict__ outf, int K, int N)
{
  __shared__ __bf16 Al[128][40];  // +8 pad: 2-way-free bank pattern on b128 reads
  __shared__ __bf16 Bl[128][40];
  const int t = threadIdx.x;
  const int lane = t & 63, w = t >> 6;
  const int wm = w >> 1, wn = w & 1;
  const int g = lane >> 4, lr = lane & 15;
  const int m0 = blockIdx.y * 128, n0 = blockIdx.x * 128;
  const int sr = t >> 2, scol = (t & 3) * 8;   // staging: rows sr, sr+64
  f32x4 acc[4][4] = {};
  for (int k0 = 0; k0 < K; k0 += 32){
    bf16x8 a0 = ld8(A  + (size_t)(m0 + sr     )*K + k0 + scol);
    bf16x8 a1 = ld8(A  + (size_t)(m0 + sr + 64)*K + k0 + scol);
    bf16x8 b0 = ld8(Bt + (size_t)(n0 + sr     )*K + k0 + scol);
    bf16x8 b1 = ld8(Bt + (size_t)(n0 + sr + 64)*K + k0 + scol);
    __syncthreads();
    *(bf16x8*)&Al[sr][scol] = a0;  *(bf16x8*)&Al[sr+64][scol] = a1;
    *(bf16x8*)&Bl[sr][scol] = b0;  *(bf16x8*)&Bl[sr+64][scol] = b1;
    __syncthreads();
    bf16x8 af[4], bfr[4];
    #pragma unroll
    for (int i=0;i<4;i++) af[i]  = ld8(&Al[wm*64 + i*16 + lr][g*8]);
    #pragma unroll
    for (int i=0;i<4;i++) bfr[i] = ld8(&Bl[wn*64 + i*16 + lr][g*8]);
    #pragma unroll
    for (int i=0;i<4;i++)
      #pragma unroll
      for (int j=0;j<4;j++)
        acc[i][j] = __builtin_amdgcn_mfma_f32_16x16x32_bf16(af[i], bfr[j], acc[i][j], 0,0,0);
  }
  // epilogue: C/D layout col=lane&15 (n), row=(lane>>4)*4+reg (m)   [m89]
  #pragma unroll
  for (int i=0;i<4;i++)
    #pragma unroll
    for (int j=0;j<4;j++)
      #pragma unroll
      for (int q=0;q<4;q++){
        int gm = m0 + wm*64 + i*16 + g*4 + q;
        int gn = n0 + wn*64 + j*16 + lr;
        float v = acc[i][j][q] + bias[gn];
        if (EPI == 0){
          int b   = gm >> 11, s = gm & 2047;
          int sec = gn >> 11, e = gn & 2047;
          int h   = e >> 7,   d = e & 127;
          outb[(size_t)sec*8388608u + ((size_t)((b<<4)+h)*2048 + s)*128 + d] = (__bf16)v;
        } else {
          outf[(size_t)gm*N + gn] = v;
        }
      }
}

// ---------------- flash attention ----------------
// grid (S/64, B*H); block 256 = 4 waves; wave owns 16 q-rows, all 128 d.
// KV tiles of 64 staged in LDS (V transposed at stage time). Online softmax.
__global__ __launch_bounds__(256) void attn_kernel(const __bf16* __restrict__ Q,
    const __bf16* __restrict__ Kp, const __bf16* __restrict__ Vp,
    __bf16* __restrict__ O)
{
  __shared__ __bf16 Klds[64][136];   // [kv][d], +8 pad
  __shared__ __bf16 Vt[128][88];     // [d][kv], +24 pad (16B-aligned rows, 2-way banks)
  __shared__ __bf16 Plds[4][16][88]; // per-wave P [q][kv]
  const int t = threadIdx.x;
  const int lane = t & 63, w = t >> 6;
  const int g = lane >> 4, lr = lane & 15;
  const int bh = blockIdx.y, qt = blockIdx.x;
  const int rK = t >> 4, cK = t & 15;  // K staging: row rK(+16i), 16B chunk cK
  const int rV = lane;                 // V staging: kv row = lane, d-quarter = w
  const __bf16* qp    = Q  + ((size_t)bh*2048 + qt*64 + w*16) * 128;
  const __bf16* kbase = Kp + (size_t)bh*2048*128;
  const __bf16* vbase = Vp + (size_t)bh*2048*128;

  // Q fragments held in registers for the whole kernel (reused 32x)
  bf16x8 qf[4];
  #pragma unroll
  for (int ks=0; ks<4; ks++) qf[ks] = ld8(qp + (size_t)lr*128 + ks*32 + g*8);

  f32x4 oacc[8] = {};
  float mrun[4] = {-3.0e38f,-3.0e38f,-3.0e38f,-3.0e38f};
  float lrun[4] = {0.f,0.f,0.f,0.f};

  for (int kv0 = 0; kv0 < 2048; kv0 += 64){
    // ---- stage K,V (loads issued before barrier; writes after) ----
    bf16x8 kreg[4], vreg[4];
    #pragma unroll
    for (int it=0; it<4; it++)
      kreg[it] = ld8(kbase + (size_t)(kv0 + it*16 + rK)*128 + cK*8);
    #pragma unroll
    for (int j8=0; j8<4; j8++)
      vreg[j8] = ld8(vbase + (size_t)(kv0 + rV)*128 + w*32 + j8*8);
    __syncthreads();                       // prior PV reads of Klds/Vt done
    #pragma unroll
    for (int it=0; it<4; it++)
      *(bf16x8*)&Klds[it*16 + rK][cK*8] = kreg[it];
    #pragma unroll
    for (int j8=0; j8<4; j8++)
      #pragma unroll
      for (int j=0; j<8; j++)
        Vt[w*32 + j8*8 + j][rV] = vreg[j8][j];  // lane==kv -> conflict-free u16
    __syncthreads();

    // ---- scores: S[16q x 64kv] ----
    f32x4 sc[4];
    #pragma unroll
    for (int nf=0; nf<4; nf++){
      f32x4 s = {0.f,0.f,0.f,0.f};
      #pragma unroll
      for (int ks=0; ks<4; ks++){
        bf16x8 kf = ld8(&Klds[nf*16 + lr][ks*32 + g*8]);
        s = __builtin_amdgcn_mfma_f32_16x16x32_bf16(qf[ks], kf, s, 0,0,0);
      }
      sc[nf] = s * 0.08838834764831845f;   // 1/sqrt(128)
    }
    // ---- online softmax; q-row = g*4+q4, kv spread over 16 lanes x 4 nf ----
    float alpha[4];
    #pragma unroll
    for (int q4=0; q4<4; q4++){
      float mx = fmaxf(fmaxf(sc[0][q4], sc[1][q4]), fmaxf(sc[2][q4], sc[3][q4]));
      mx = fmaxf(mx, __shfl_xor(mx, 1));
      mx = fmaxf(mx, __shfl_xor(mx, 2));
      mx = fmaxf(mx, __shfl_xor(mx, 4));
      mx = fmaxf(mx, __shfl_xor(mx, 8));
      float mnew = fmaxf(mrun[q4], mx);
      alpha[q4] = __expf(mrun[q4] - mnew);
      mrun[q4] = mnew;
      float sum = 0.f;
      #pragma unroll
      for (int nf=0; nf<4; nf++){
        float p = __expf(sc[nf][q4] - mnew);
        sc[nf][q4] = p;
        sum += p;
      }
      sum += __shfl_xor(sum, 1);
      sum += __shfl_xor(sum, 2);
      sum += __shfl_xor(sum, 4);
      sum += __shfl_xor(sum, 8);
      lrun[q4] = lrun[q4]*alpha[q4] + sum;
    }
    // ---- P -> LDS (bf16), rescale O ----
    #pragma unroll
    for (int nf=0; nf<4; nf++)
      #pragma unroll
      for (int q4=0; q4<4; q4++)
        Plds[w][g*4 + q4][nf*16 + lr] = (__bf16)sc[nf][q4];
    #pragma unroll
    for (int nf2=0; nf2<8; nf2++)
      #pragma unroll
      for (int q4=0; q4<4; q4++)
        oacc[nf2][q4] *= alpha[q4];
    __syncthreads();
    // ---- PV: O[16q x 128d] += P[16q x 64kv] * V[64kv x 128d] ----
    bf16x8 pf[2];
    #pragma unroll
    for (int ks2=0; ks2<2; ks2++)
      pf[ks2] = ld8(&Plds[w][lr][ks2*32 + g*8]);
    #pragma unroll
    for (int nf2=0; nf2<8; nf2++)
      #pragma unroll
      for (int ks2=0; ks2<2; ks2++){
        bf16x8 vf = ld8(&Vt[nf2*16 + lr][ks2*32 + g*8]);
        oacc[nf2] = __builtin_amdgcn_mfma_f32_16x16x32_bf16(pf[ks2], vf, oacc[nf2], 0,0,0);
      }
  }
  // ---- epilogue: attb[b, s, h*128+d] bf16 ----
  const int b = bh >> 4, h = bh & 15;
  __bf16* op = O + ((size_t)b*2048 + qt*64 + w*16)*2048 + h*128;
  float inv[4];
  #pragma unroll
  for (int q4=0;q4<4;q4++) inv[q4] = 1.0f / lrun[q4];
  #pragma unroll
  for (int nf2=0; nf2<8; nf2++)
    #pragma unroll
    for (int q4=0; q4<4; q4++)
      op[(size_t)(g*4 + q4)*2048 + nf2*16 + lr] = (__bf16)(oacc[nf2][q4] * inv[q4]);
}

extern "C" void kernel_launch(void* const* d_in, const int* in_sizes, int n_in,
                              void* d_out, int out_size, void* d_ws, size_t ws_size,
                              hipStream_t stream) {
  const float* x     = (const float*)d_in[0];
  const float* Wqkv  = (const float*)d_in[1];
  const float* bqkv  = (const float*)d_in[2];
  const float* Wproj = (const float*)d_in[3];
  const float* bproj = (const float*)d_in[4];
  float* out = (float*)d_out;

  __bf16* xb     = (__bf16*)d_ws;                       // [4096][2048]
  __bf16* wqkvT  = xb     + (size_t)4096*2048;          // [6144][2048]
  __bf16* wprojT = wqkvT  + (size_t)6144*2048;          // [2048][2048]
  __bf16* qq     = wprojT + (size_t)2048*2048;          // [32][2048][128]
  __bf16* kk     = qq     + (size_t)32*2048*128;
  __bf16* vv     = kk     + (size_t)32*2048*128;
  __bf16* attb   = vv     + (size_t)32*2048*128;        // [4096][2048]

  cvt_kernel<<<2048, 256, 0, stream>>>(x, xb, (4096*2048)/4);
  transcvt_kernel<<<dim3(6144/32, 2048/32), 256, 0, stream>>>(Wqkv, wqkvT, 2048, 6144);
  transcvt_kernel<<<dim3(2048/32, 2048/32), 256, 0, stream>>>(Wproj, wprojT, 2048, 2048);
  gemm_bt<0><<<dim3(6144/128, 4096/128), 256, 0, stream>>>(xb, wqkvT, bqkv, qq, nullptr, 2048, 6144);
  attn_kernel<<<dim3(2048/64, 32), 256, 0, stream>>>(qq, kk, vv, attb);
  gemm_bt<1><<<dim3(2048/128, 4096/128), 256, 0, stream>>>(attb, wprojT, bproj, nullptr, out, 2048, 2048);
}

// Round 2
// 519.679 us; speedup vs baseline: 1.0279x; 1.0279x over previous
//
#include <hip/hip_runtime.h>
#include <hip/hip_bf16.h>

// Fused MHA forward for MI355X (gfx950).
// B=2, S=2048, E=2048, H=16, D=128.
// Pipeline: cvt(x)->bf16 ; transcvt(W)->bf16 [N,K] ; GEMM1(qkv,+bias, scatter to
// [B,H,S,D]) ; flash-attn ; GEMM2(+bias)->fp32 out.
// R2: GEMMs use m97 structure — linear LDS + global_load_lds width-16.

typedef __bf16 bf16x8 __attribute__((ext_vector_type(8)));
typedef __bf16 bf16x4 __attribute__((ext_vector_type(4)));
typedef float  f32x4  __attribute__((ext_vector_type(4)));

static __device__ __forceinline__ bf16x8 ld8(const __bf16* p){
  return *reinterpret_cast<const bf16x8*>(p);
}

#define GLOAD_LDS16(gsrc, ldst) \
  __builtin_amdgcn_global_load_lds((const __attribute__((address_space(1))) void*)(gsrc), \
                                   (__attribute__((address_space(3))) void*)(ldst), 16, 0, 0)

// ---------------- fp32 -> bf16 elementwise ----------------
__global__ __launch_bounds__(256) void cvt_kernel(const float* __restrict__ src,
                                                  __bf16* __restrict__ dst, int n4){
  int stride = gridDim.x * blockDim.x;
  for (int i = blockIdx.x*blockDim.x + threadIdx.x; i < n4; i += stride){
    float4 v = reinterpret_cast<const float4*>(src)[i];
    bf16x4 o;
    o[0] = (__bf16)v.x; o[1] = (__bf16)v.y; o[2] = (__bf16)v.z; o[3] = (__bf16)v.w;
    reinterpret_cast<bf16x4*>(dst)[i] = o;
  }
}

// ---------------- fp32 [K][N] -> bf16 [N][K] (transpose + cast) ----------------
__global__ __launch_bounds__(256) void transcvt_kernel(const float* __restrict__ src,
                                                       __bf16* __restrict__ dst,
                                                       int K, int N){
  __shared__ float tile[32][33];
  const int n0 = blockIdx.x*32, k0 = blockIdx.y*32;
  const int tx = threadIdx.x & 31, ty = threadIdx.x >> 5;
  #pragma unroll
  for (int i = 0; i < 32; i += 8)
    tile[ty+i][tx] = src[(size_t)(k0+ty+i)*N + n0 + tx];
  __syncthreads();
  #pragma unroll
  for (int i = 0; i < 32; i += 8)
    dst[(size_t)(n0+ty+i)*K + k0 + tx] = (__bf16)tile[tx][ty+i];
}

// ---------------- bf16 GEMM: C[M,N] = A[M,K] * Bt[N,K]^T + bias ----------------
// m97 structure: 128x128 tile, 4 waves (2x2), each wave 64x64 = 4x4 MFMA frags,
// BK=32, LINEAR LDS (8 KB per operand), global_load_lds dwordx4 staging.
// EPI 0: scatter bf16 into q/k/v [B,H,S,D];  EPI 1: fp32 C + bias.
template<int EPI>
__global__ __launch_bounds__(256) void gemm_bt(const __bf16* __restrict__ A,
    const __bf16* __restrict__ Bt, const float* __restrict__ bias,
    __bf16* __restrict__ outb, float* __restrict__ outf, int K, int N)
{
  __shared__ __bf16 Al[128*32];   // linear [row][32] — gload_lds needs contiguity
  __shared__ __bf16 Bl[128*32];
  const int t = threadIdx.x;
  const int lane = t & 63, w = t >> 6;
  const int wm = w >> 1, wn = w & 1;
  const int g = lane >> 4, lr = lane & 15;
  const int m0 = blockIdx.y * 128, n0 = blockIdx.x * 128;
  // staging: wave w covers rows [w*32, w*32+32) in two 16-row (1 KB) chunks.
  // lane covers row w*32 + i*16 + lane/4, cols (lane&3)*8 .. +8  (16 B)
  const int srow = lane >> 2, scol = (lane & 3)*8;
  const __bf16* aS = A  + (size_t)(m0 + w*32 + srow)*K + scol;
  const __bf16* bS = Bt + (size_t)(n0 + w*32 + srow)*K + scol;
  const int ldsOff = (w*32 + srow)*32 + scol;     // elements; lane0 = wave base
  f32x4 acc[4][4] = {};
  for (int k0 = 0; k0 < K; k0 += 32){
    __syncthreads();                              // prior iter's LDS reads done
    GLOAD_LDS16(aS + k0,          Al + ldsOff);
    GLOAD_LDS16(aS + k0 + 16*K,   Al + ldsOff + 512);
    GLOAD_LDS16(bS + k0,          Bl + ldsOff);
    GLOAD_LDS16(bS + k0 + 16*K,   Bl + ldsOff + 512);
    __syncthreads();                              // drains vmcnt(0) before barrier
    bf16x8 af[4], bfr[4];
    #pragma unroll
    for (int i=0;i<4;i++) af[i]  = ld8(&Al[(wm*64 + i*16 + lr)*32 + g*8]);
    #pragma unroll
    for (int i=0;i<4;i++) bfr[i] = ld8(&Bl[(wn*64 + i*16 + lr)*32 + g*8]);
    #pragma unroll
    for (int i=0;i<4;i++)
      #pragma unroll
      for (int j=0;j<4;j++)
        acc[i][j] = __builtin_amdgcn_mfma_f32_16x16x32_bf16(af[i], bfr[j], acc[i][j], 0,0,0);
  }
  // epilogue: C/D layout col=lane&15 (n), row=(lane>>4)*4+reg (m)   [m89]
  #pragma unroll
  for (int i=0;i<4;i++)
    #pragma unroll
    for (int j=0;j<4;j++)
      #pragma unroll
      for (int q=0;q<4;q++){
        int gm = m0 + wm*64 + i*16 + g*4 + q;
        int gn = n0 + wn*64 + j*16 + lr;
        float v = acc[i][j][q] + bias[gn];
        if (EPI == 0){
          int b   = gm >> 11, s = gm & 2047;
          int sec = gn >> 11, e = gn & 2047;
          int h   = e >> 7,   d = e & 127;
          outb[(size_t)sec*8388608u + ((size_t)((b<<4)+h)*2048 + s)*128 + d] = (__bf16)v;
        } else {
          outf[(size_t)gm*N + gn] = v;
        }
      }
}

// ---------------- flash attention ----------------
// grid (S/64, B*H); block 256 = 4 waves; wave owns 16 q-rows, all 128 d.
// KV tiles of 64 staged in LDS (V transposed at stage time). Online softmax.
__global__ __launch_bounds__(256) void attn_kernel(const __bf16* __restrict__ Q,
    const __bf16* __restrict__ Kp, const __bf16* __restrict__ Vp,
    __bf16* __restrict__ O)
{
  __shared__ __bf16 Klds[64][136];   // [kv][d], +8 pad
  __shared__ __bf16 Vt[128][88];     // [d][kv], +24 pad (16B-aligned rows, 2-way banks)
  __shared__ __bf16 Plds[4][16][88]; // per-wave P [q][kv]
  const int t = threadIdx.x;
  const int lane = t & 63, w = t >> 6;
  const int g = lane >> 4, lr = lane & 15;
  const int bh = blockIdx.y, qt = blockIdx.x;
  const int rK = t >> 4, cK = t & 15;  // K staging: row rK(+16i), 16B chunk cK
  const int rV = lane;                 // V staging: kv row = lane, d-quarter = w
  const __bf16* qp    = Q  + ((size_t)bh*2048 + qt*64 + w*16) * 128;
  const __bf16* kbase = Kp + (size_t)bh*2048*128;
  const __bf16* vbase = Vp + (size_t)bh*2048*128;

  // Q fragments held in registers for the whole kernel (reused 32x)
  bf16x8 qf[4];
  #pragma unroll
  for (int ks=0; ks<4; ks++) qf[ks] = ld8(qp + (size_t)lr*128 + ks*32 + g*8);

  f32x4 oacc[8] = {};
  float mrun[4] = {-3.0e38f,-3.0e38f,-3.0e38f,-3.0e38f};
  float lrun[4] = {0.f,0.f,0.f,0.f};

  for (int kv0 = 0; kv0 < 2048; kv0 += 64){
    // ---- stage K,V (loads issued before barrier; writes after) ----
    bf16x8 kreg[4], vreg[4];
    #pragma unroll
    for (int it=0; it<4; it++)
      kreg[it] = ld8(kbase + (size_t)(kv0 + it*16 + rK)*128 + cK*8);
    #pragma unroll
    for (int j8=0; j8<4; j8++)
      vreg[j8] = ld8(vbase + (size_t)(kv0 + rV)*128 + w*32 + j8*8);
    __syncthreads();                       // prior PV reads of Klds/Vt done
    #pragma unroll
    for (int it=0; it<4; it++)
      *(bf16x8*)&Klds[it*16 + rK][cK*8] = kreg[it];
    #pragma unroll
    for (int j8=0; j8<4; j8++)
      #pragma unroll
      for (int j=0; j<8; j++)
        Vt[w*32 + j8*8 + j][rV] = vreg[j8][j];  // lane==kv -> conflict-free u16
    __syncthreads();

    // ---- scores: S[16q x 64kv] ----
    f32x4 sc[4];
    #pragma unroll
    for (int nf=0; nf<4; nf++){
      f32x4 s = {0.f,0.f,0.f,0.f};
      #pragma unroll
      for (int ks=0; ks<4; ks++){
        bf16x8 kf = ld8(&Klds[nf*16 + lr][ks*32 + g*8]);
        s = __builtin_amdgcn_mfma_f32_16x16x32_bf16(qf[ks], kf, s, 0,0,0);
      }
      sc[nf] = s * 0.08838834764831845f;   // 1/sqrt(128)
    }
    // ---- online softmax; q-row = g*4+q4, kv spread over 16 lanes x 4 nf ----
    float alpha[4];
    #pragma unroll
    for (int q4=0; q4<4; q4++){
      float mx = fmaxf(fmaxf(sc[0][q4], sc[1][q4]), fmaxf(sc[2][q4], sc[3][q4]));
      mx = fmaxf(mx, __shfl_xor(mx, 1));
      mx = fmaxf(mx, __shfl_xor(mx, 2));
      mx = fmaxf(mx, __shfl_xor(mx, 4));
      mx = fmaxf(mx, __shfl_xor(mx, 8));
      float mnew = fmaxf(mrun[q4], mx);
      alpha[q4] = __expf(mrun[q4] - mnew);
      mrun[q4] = mnew;
      float sum = 0.f;
      #pragma unroll
      for (int nf=0; nf<4; nf++){
        float p = __expf(sc[nf][q4] - mnew);
        sc[nf][q4] = p;
        sum += p;
      }
      sum += __shfl_xor(sum, 1);
      sum += __shfl_xor(sum, 2);
      sum += __shfl_xor(sum, 4);
      sum += __shfl_xor(sum, 8);
      lrun[q4] = lrun[q4]*alpha[q4] + sum;
    }
    // ---- P -> LDS (bf16), rescale O ----
    #pragma unroll
    for (int nf=0; nf<4; nf++)
      #pragma unroll
      for (int q4=0; q4<4; q4++)
        Plds[w][g*4 + q4][nf*16 + lr] = (__bf16)sc[nf][q4];
    #pragma unroll
    for (int nf2=0; nf2<8; nf2++)
      #pragma unroll
      for (int q4=0; q4<4; q4++)
        oacc[nf2][q4] *= alpha[q4];
    __syncthreads();
    // ---- PV: O[16q x 128d] += P[16q x 64kv] * V[64kv x 128d] ----
    bf16x8 pf[2];
    #pragma unroll
    for (int ks2=0; ks2<2; ks2++)
      pf[ks2] = ld8(&Plds[w][lr][ks2*32 + g*8]);
    #pragma unroll
    for (int nf2=0; nf2<8; nf2++)
      #pragma unroll
      for (int ks2=0; ks2<2; ks2++){
        bf16x8 vf = ld8(&Vt[nf2*16 + lr][ks2*32 + g*8]);
        oacc[nf2] = __builtin_amdgcn_mfma_f32_16x16x32_bf16(pf[ks2], vf, oacc[nf2], 0,0,0);
      }
  }
  // ---- epilogue: attb[b, s, h*128+d] bf16 ----
  const int b = bh >> 4, h = bh & 15;
  __bf16* op = O + ((size_t)b*2048 + qt*64 + w*16)*2048 + h*128;
  float inv[4];
  #pragma unroll
  for (int q4=0;q4<4;q4++) inv[q4] = 1.0f / lrun[q4];
  #pragma unroll
  for (int nf2=0; nf2<8; nf2++)
    #pragma unroll
    for (int q4=0; q4<4; q4++)
      op[(size_t)(g*4 + q4)*2048 + nf2*16 + lr] = (__bf16)(oacc[nf2][q4] * inv[q4]);
}

extern "C" void kernel_launch(void* const* d_in, const int* in_sizes, int n_in,
                              void* d_out, int out_size, void* d_ws, size_t ws_size,
                              hipStream_t stream) {
  const float* x     = (const float*)d_in[0];
  const float* Wqkv  = (const float*)d_in[1];
  const float* bqkv  = (const float*)d_in[2];
  const float* Wproj = (const float*)d_in[3];
  const float* bproj = (const float*)d_in[4];
  float* out = (float*)d_out;

  __bf16* xb     = (__bf16*)d_ws;                       // [4096][2048]
  __bf16* wqkvT  = xb     + (size_t)4096*2048;          // [6144][2048]
  __bf16* wprojT = wqkvT  + (size_t)6144*2048;          // [2048][2048]
  __bf16* qq     = wprojT + (size_t)2048*2048;          // [32][2048][128]
  __bf16* kk     = qq     + (size_t)32*2048*128;
  __bf16* vv     = kk     + (size_t)32*2048*128;
  __bf16* attb   = vv     + (size_t)32*2048*128;        // [4096][2048]

  cvt_kernel<<<2048, 256, 0, stream>>>(x, xb, (4096*2048)/4);
  transcvt_kernel<<<dim3(6144/32, 2048/32), 256, 0, stream>>>(Wqkv, wqkvT, 2048, 6144);
  transcvt_kernel<<<dim3(2048/32, 2048/32), 256, 0, stream>>>(Wproj, wprojT, 2048, 2048);
  gemm_bt<0><<<dim3(6144/128, 4096/128), 256, 0, stream>>>(xb, wqkvT, bqkv, qq, nullptr, 2048, 6144);
  attn_kernel<<<dim3(2048/64, 32), 256, 0, stream>>>(qq, kk, vv, attb);
  gemm_bt<1><<<dim3(2048/128, 4096/128), 256, 0, stream>>>(attb, wprojT, bproj, nullptr, out, 2048, 2048);
}

// Round 3
// 489.555 us; speedup vs baseline: 1.0911x; 1.0615x over previous
//
#include <hip/hip_runtime.h>
#include <hip/hip_bf16.h>

// Fused MHA forward for MI355X (gfx950).
// B=2, S=2048, E=2048, H=16, D=128.
// R3: attn rewritten as 8-warp 32x32 swapped-QK^T flash kernel (guide §B):
//   - K in LDS, XOR-swizzled via pre-swizzled global_load_lds source
//   - softmax fully in-register (P-row lane-local), defer-max THR=8
//   - P->bf16 via v_cvt_pk_bf16_f32 + v_permlane32_swap_b32
//   - PV computed as O^T = V^T * P^T so m/l/alpha stay per-lane
//   - O^T -> O transpose through reused LDS, coalesced 64B-run stores
//   - XCD-aware block decode: 8 q-tiles of one (b,h) share an XCD (KV L2-resident)

typedef __bf16 bf16x8 __attribute__((ext_vector_type(8)));
typedef __bf16 bf16x4 __attribute__((ext_vector_type(4)));
typedef float  f32x4  __attribute__((ext_vector_type(4)));
typedef float  f32x16 __attribute__((ext_vector_type(16)));

static __device__ __forceinline__ bf16x8 ld8(const __bf16* p){
  return *reinterpret_cast<const bf16x8*>(p);
}

#define GLOAD_LDS16(gsrc, ldst) \
  __builtin_amdgcn_global_load_lds((const __attribute__((address_space(1))) void*)(gsrc), \
                                   (__attribute__((address_space(3))) void*)(ldst), 16, 0, 0)

static __device__ __forceinline__ unsigned cvtpk(float lo, float hi){
  unsigned r; asm("v_cvt_pk_bf16_f32 %0, %1, %2" : "=v"(r) : "v"(lo), "v"(hi)); return r;
}
#define PLSWAP(a, b) asm volatile("v_permlane32_swap_b32 %0, %1" : "+v"(a), "+v"(b))

// ---------------- fp32 -> bf16 elementwise ----------------
__global__ __launch_bounds__(256) void cvt_kernel(const float* __restrict__ src,
                                                  __bf16* __restrict__ dst, int n4){
  int stride = gridDim.x * blockDim.x;
  for (int i = blockIdx.x*blockDim.x + threadIdx.x; i < n4; i += stride){
    float4 v = reinterpret_cast<const float4*>(src)[i];
    bf16x4 o;
    o[0] = (__bf16)v.x; o[1] = (__bf16)v.y; o[2] = (__bf16)v.z; o[3] = (__bf16)v.w;
    reinterpret_cast<bf16x4*>(dst)[i] = o;
  }
}

// ---------------- fp32 [K][N] -> bf16 [N][K] (transpose + cast) ----------------
__global__ __launch_bounds__(256) void transcvt_kernel(const float* __restrict__ src,
                                                       __bf16* __restrict__ dst,
                                                       int K, int N){
  __shared__ float tile[32][33];
  const int n0 = blockIdx.x*32, k0 = blockIdx.y*32;
  const int tx = threadIdx.x & 31, ty = threadIdx.x >> 5;
  #pragma unroll
  for (int i = 0; i < 32; i += 8)
    tile[ty+i][tx] = src[(size_t)(k0+ty+i)*N + n0 + tx];
  __syncthreads();
  #pragma unroll
  for (int i = 0; i < 32; i += 8)
    dst[(size_t)(n0+ty+i)*K + k0 + tx] = (__bf16)tile[tx][ty+i];
}

// ---------------- bf16 GEMM: C[M,N] = A[M,K] * Bt[N,K]^T + bias ----------------
template<int EPI>
__global__ __launch_bounds__(256) void gemm_bt(const __bf16* __restrict__ A,
    const __bf16* __restrict__ Bt, const float* __restrict__ bias,
    __bf16* __restrict__ outb, float* __restrict__ outf, int K, int N)
{
  __shared__ __bf16 Al[128*32];
  __shared__ __bf16 Bl[128*32];
  const int t = threadIdx.x;
  const int lane = t & 63, w = t >> 6;
  const int wm = w >> 1, wn = w & 1;
  const int g = lane >> 4, lr = lane & 15;
  const int m0 = blockIdx.y * 128, n0 = blockIdx.x * 128;
  const int srow = lane >> 2, scol = (lane & 3)*8;
  const __bf16* aS = A  + (size_t)(m0 + w*32 + srow)*K + scol;
  const __bf16* bS = Bt + (size_t)(n0 + w*32 + srow)*K + scol;
  const int ldsOff = (w*32 + srow)*32 + scol;
  f32x4 acc[4][4] = {};
  for (int k0 = 0; k0 < K; k0 += 32){
    __syncthreads();
    GLOAD_LDS16(aS + k0,          Al + ldsOff);
    GLOAD_LDS16(aS + k0 + 16*K,   Al + ldsOff + 512);
    GLOAD_LDS16(bS + k0,          Bl + ldsOff);
    GLOAD_LDS16(bS + k0 + 16*K,   Bl + ldsOff + 512);
    __syncthreads();
    bf16x8 af[4], bfr[4];
    #pragma unroll
    for (int i=0;i<4;i++) af[i]  = ld8(&Al[(wm*64 + i*16 + lr)*32 + g*8]);
    #pragma unroll
    for (int i=0;i<4;i++) bfr[i] = ld8(&Bl[(wn*64 + i*16 + lr)*32 + g*8]);
    #pragma unroll
    for (int i=0;i<4;i++)
      #pragma unroll
      for (int j=0;j<4;j++)
        acc[i][j] = __builtin_amdgcn_mfma_f32_16x16x32_bf16(af[i], bfr[j], acc[i][j], 0,0,0);
  }
  #pragma unroll
  for (int i=0;i<4;i++)
    #pragma unroll
    for (int j=0;j<4;j++)
      #pragma unroll
      for (int q=0;q<4;q++){
        int gm = m0 + wm*64 + i*16 + g*4 + q;
        int gn = n0 + wn*64 + j*16 + lr;
        float v = acc[i][j][q] + bias[gn];
        if (EPI == 0){
          int b   = gm >> 11, s = gm & 2047;
          int sec = gn >> 11, e = gn & 2047;
          int h   = e >> 7,   d = e & 127;
          outb[(size_t)sec*8388608u + ((size_t)((b<<4)+h)*2048 + s)*128 + d] = (__bf16)v;
        } else {
          outf[(size_t)gm*N + gn] = v;
        }
      }
}

// ---------------- flash attention, 8-warp 32x32 swapped structure ----------------
// grid 256 blocks x 512 threads. Block = (bh, qt): 256 q rows; warp owns 32.
// K_lds[64][128] XOR-swizzled (16B slot ^= kv&15), double-buffered.
// Vt[128][68] = V^T (stride 68 -> 2-way-free b64 reads).
// S^T = K*Q^T via mfma(Kfrag, Qfrag): lane holds P[q=lane&31][32 kv regs].
// O^T = V^T*P^T via mfma(Vfrag, Pfrag): col=q=lane&31 -> per-lane m/l/alpha.
__global__ __launch_bounds__(512, 2) void attn_kernel(const __bf16* __restrict__ Q,
    const __bf16* __restrict__ Kp, const __bf16* __restrict__ Vp,
    __bf16* __restrict__ O)
{
  __shared__ union {
    struct { __bf16 k[2][64*128]; __bf16 vt[128*68]; } a;  // 50176 B
    __bf16 ot[8][32*68];                                    // 34816 B
  } sm;
  const int t = threadIdx.x;
  const int lane = t & 63, w = t >> 6;
  const int q31 = lane & 31, hi = lane >> 5;
  // XCD-aware decode: 8 q-tiles of one (b,h) -> same XCD
  const int bid = blockIdx.x;
  const int bh = (bid & 7) * 4 + ((bid >> 3) >> 3);
  const int qt = (bid >> 3) & 7;
  const int q0 = qt * 256 + w * 32;
  const __bf16* kbase = Kp + (size_t)bh * 2048 * 128;
  const __bf16* vbase = Vp + (size_t)bh * 2048 * 128;

  // Q fragments: qf[kc][j] = Q[q0+q31][kc*16 + hi*8 + j]
  const __bf16* qp = Q + ((size_t)bh*2048 + q0 + q31) * 128;
  bf16x8 qf[8];
  #pragma unroll
  for (int kc = 0; kc < 8; kc++) qf[kc] = ld8(qp + kc*16 + hi*8);

  // K staging (pre-swizzled source; LDS dest linear = wave base + lane*16B)
  const int skv  = w*4 + (lane >> 4);            // row within 32-row chunk
  const int sxor = ((lane & 15) ^ (skv & 15)) * 8;
  const int kldsOff = w*512 + lane*8;            // elems
  // V reg staging: lane reads V[kv0+lane][w*16 .. +16]
  const __bf16* vsrc = vbase + (size_t)lane * 128 + w * 16;

  // prologue: stage tile 0
  GLOAD_LDS16(kbase + (size_t)(skv     )*128 + sxor, sm.a.k[0] + kldsOff);
  GLOAD_LDS16(kbase + (size_t)(skv + 32)*128 + sxor, sm.a.k[0] + kldsOff + 4096);
  bf16x8 vr0 = ld8(vsrc), vr1 = ld8(vsrc + 8);

  f32x16 oacc[4] = {};
  float mrun = -1e30f, lrun = 0.f;
  const float C = 0.127517912f;   // (1/sqrt(128)) * log2(e)
  const int swz = (q31 & 15);     // kv&15 for both halves

  for (int t64 = 0; t64 < 32; t64++){
    __syncthreads();              // K(t) drained; prior PV reads of Vt done
    // write V^T from regs (2-way bank pattern -> free)
    #pragma unroll
    for (int e = 0; e < 8; e++) sm.a.vt[(w*16 + e)*68 + lane] = vr0[e];
    #pragma unroll
    for (int e = 0; e < 8; e++) sm.a.vt[(w*16 + 8 + e)*68 + lane] = vr1[e];
    __syncthreads();              // Vt visible
    const __bf16* kb = sm.a.k[t64 & 1];
    if (t64 + 1 < 32){            // prefetch next tile under this tile's compute
      const int kvn = (t64 + 1) * 64;
      __bf16* kd = sm.a.k[(t64 + 1) & 1] + kldsOff;
      GLOAD_LDS16(kbase + (size_t)(kvn + skv     )*128 + sxor, kd);
      GLOAD_LDS16(kbase + (size_t)(kvn + skv + 32)*128 + sxor, kd + 4096);
      vr0 = ld8(vsrc + (size_t)kvn*128);
      vr1 = ld8(vsrc + (size_t)kvn*128 + 8);
    }
    // ---- S^T[kv][q]: two 32x32 blocks over D=128 ----
    f32x16 s0 = {}, s1 = {};
    #pragma unroll
    for (int kc = 0; kc < 8; kc++){
      const int sl = (((kc<<1) | hi) ^ swz) * 8;
      bf16x8 k0 = ld8(kb + (size_t)q31*128 + sl);
      bf16x8 k1 = ld8(kb + (size_t)(q31 + 32)*128 + sl);
      s0 = __builtin_amdgcn_mfma_f32_32x32x16_bf16(k0, qf[kc], s0, 0,0,0);
      s1 = __builtin_amdgcn_mfma_f32_32x32x16_bf16(k1, qf[kc], s1, 0,0,0);
    }
    // ---- in-register online softmax (q = lane&31 fixed per lane) ----
    float pm = s0[0];
    #pragma unroll
    for (int r = 1; r < 16; r++) pm = fmaxf(pm, s0[r]);
    #pragma unroll
    for (int r = 0; r < 16; r++) pm = fmaxf(pm, s1[r]);
    pm = fmaxf(pm, __shfl_xor(pm, 32));
    if (!__all(pm <= mrun + 90.51f)){   // defer-max: 8/scale in raw units
      float mnew = fmaxf(mrun, pm);
      float al = exp2f((mrun - mnew) * C);
      mrun = mnew; lrun *= al;
      #pragma unroll
      for (int d = 0; d < 4; d++)
        #pragma unroll
        for (int r = 0; r < 16; r++) oacc[d][r] *= al;
    }
    float p[32];
    #pragma unroll
    for (int r = 0; r < 16; r++){
      p[r]      = exp2f((s0[r] - mrun) * C);
      p[16 + r] = exp2f((s1[r] - mrun) * C);
    }
    float ls = 0.f;
    #pragma unroll
    for (int r = 0; r < 32; r++) ls += p[r];
    ls += __shfl_xor(ls, 32);
    lrun += ls;
    // ---- pack P -> bf16 PA fragments (cvt_pk + permlane32_swap) ----
    bf16x8 pa[4];
    #pragma unroll
    for (int ks = 0; ks < 4; ks++){
      unsigned a0 = cvtpk(p[8*ks    ], p[8*ks + 1]);
      unsigned a1 = cvtpk(p[8*ks + 2], p[8*ks + 3]);
      unsigned b0 = cvtpk(p[8*ks + 4], p[8*ks + 5]);
      unsigned b1 = cvtpk(p[8*ks + 6], p[8*ks + 7]);
      PLSWAP(a0, b0); PLSWAP(a1, b1);
      union { unsigned u[4]; bf16x8 v; } pw;
      pw.u[0] = a0; pw.u[1] = a1; pw.u[2] = b0; pw.u[3] = b1;
      pa[ks] = pw.v;
    }
    // ---- O^T += V^T * P^T ----
    #pragma unroll
    for (int db = 0; db < 4; db++){
      const int d = db*32 + q31;
      #pragma unroll
      for (int ks = 0; ks < 4; ks++){
        bf16x4 vlo = *(const bf16x4*)&sm.a.vt[d*68 + ks*16 + hi*8];
        bf16x4 vhi = *(const bf16x4*)&sm.a.vt[d*68 + ks*16 + hi*8 + 4];
        bf16x8 vf;
        #pragma unroll
        for (int j = 0; j < 4; j++){ vf[j] = vlo[j]; vf[4+j] = vhi[j]; }
        oacc[db] = __builtin_amdgcn_mfma_f32_32x32x16_bf16(vf, pa[ks], oacc[db], 0,0,0);
      }
    }
  }
  // ---- epilogue: O^T -> O via per-warp LDS transpose, coalesced store ----
  __syncthreads();                 // done with kbuf/vt; reuse as ot
  const float invl = 1.0f / lrun;
  __bf16* ow = sm.ot[w];
  const int b = bh >> 4, h = bh & 15;
  #pragma unroll
  for (int pass = 0; pass < 2; pass++){
    #pragma unroll
    for (int which = 0; which < 2; which++)
      #pragma unroll
      for (int r = 0; r < 16; r++){
        const int dloc = which*32 + (r & 3) + 8*(r >> 2) + 4*hi;
        ow[q31*68 + dloc] = (__bf16)(oacc[pass*2 + which][r] * invl);
      }
    #pragma unroll
    for (int it = 0; it < 4; it++){
      const int sl = (lane >> 3) + it*8;
      const int ch = lane & 7;
      bf16x4 r0 = *(const bf16x4*)&ow[sl*68 + ch*8];
      bf16x4 r1 = *(const bf16x4*)&ow[sl*68 + ch*8 + 4];
      bf16x8 o8;
      #pragma unroll
      for (int j = 0; j < 4; j++){ o8[j] = r0[j]; o8[4+j] = r1[j]; }
      *(bf16x8*)&O[((size_t)(b*2048 + q0 + sl))*2048 + h*128 + pass*64 + ch*8] = o8;
    }
  }
}

extern "C" void kernel_launch(void* const* d_in, const int* in_sizes, int n_in,
                              void* d_out, int out_size, void* d_ws, size_t ws_size,
                              hipStream_t stream) {
  const float* x     = (const float*)d_in[0];
  const float* Wqkv  = (const float*)d_in[1];
  const float* bqkv  = (const float*)d_in[2];
  const float* Wproj = (const float*)d_in[3];
  const float* bproj = (const float*)d_in[4];
  float* out = (float*)d_out;

  __bf16* xb     = (__bf16*)d_ws;                       // [4096][2048]
  __bf16* wqkvT  = xb     + (size_t)4096*2048;          // [6144][2048]
  __bf16* wprojT = wqkvT  + (size_t)6144*2048;          // [2048][2048]
  __bf16* qq     = wprojT + (size_t)2048*2048;          // [32][2048][128]
  __bf16* kk     = qq     + (size_t)32*2048*128;
  __bf16* vv     = kk     + (size_t)32*2048*128;
  __bf16* attb   = vv     + (size_t)32*2048*128;        // [4096][2048]

  cvt_kernel<<<2048, 256, 0, stream>>>(x, xb, (4096*2048)/4);
  transcvt_kernel<<<dim3(6144/32, 2048/32), 256, 0, stream>>>(Wqkv, wqkvT, 2048, 6144);
  transcvt_kernel<<<dim3(2048/32, 2048/32), 256, 0, stream>>>(Wproj, wprojT, 2048, 2048);
  gemm_bt<0><<<dim3(6144/128, 4096/128), 256, 0, stream>>>(xb, wqkvT, bqkv, qq, nullptr, 2048, 6144);
  attn_kernel<<<256, 512, 0, stream>>>(qq, kk, vv, attb);
  gemm_bt<1><<<dim3(2048/128, 4096/128), 256, 0, stream>>>(attb, wprojT, bproj, nullptr, out, 2048, 2048);
}

// Round 4
// 446.333 us; speedup vs baseline: 1.1968x; 1.0968x over previous
//
#include <hip/hip_runtime.h>
#include <hip/hip_bf16.h>

// Fused MHA forward for MI355X (gfx950).  B=2, S=2048, E=2048, H=16, D=128.
// R4: attn -> 16-q-row waves (4096 waves = 4/SIMD occupancy), KVBLK=32,
//     row-permuted QK^T so softmax+PV fragments are fully lane-local.
//     GEMMs -> LDS-transpose epilogue (b128 stores) + XCD-swizzled 1D grid.

typedef __bf16 bf16x8 __attribute__((ext_vector_type(8)));
typedef __bf16 bf16x4 __attribute__((ext_vector_type(4)));
typedef float  f32x4  __attribute__((ext_vector_type(4)));

static __device__ __forceinline__ bf16x8 ld8(const __bf16* p){
  return *reinterpret_cast<const bf16x8*>(p);
}

#define GLOAD_LDS16(gsrc, ldst) \
  __builtin_amdgcn_global_load_lds((const __attribute__((address_space(1))) void*)(gsrc), \
                                   (__attribute__((address_space(3))) void*)(ldst), 16, 0, 0)

static __device__ __forceinline__ unsigned cvtpk(float lo, float hi){
  unsigned r; asm("v_cvt_pk_bf16_f32 %0, %1, %2" : "=v"(r) : "v"(lo), "v"(hi)); return r;
}

// ---------------- fp32 -> bf16 elementwise ----------------
__global__ __launch_bounds__(256) void cvt_kernel(const float* __restrict__ src,
                                                  __bf16* __restrict__ dst, int n4){
  int stride = gridDim.x * blockDim.x;
  for (int i = blockIdx.x*blockDim.x + threadIdx.x; i < n4; i += stride){
    float4 v = reinterpret_cast<const float4*>(src)[i];
    bf16x4 o;
    o[0] = (__bf16)v.x; o[1] = (__bf16)v.y; o[2] = (__bf16)v.z; o[3] = (__bf16)v.w;
    reinterpret_cast<bf16x4*>(dst)[i] = o;
  }
}

// ---------------- fp32 [K][N] -> bf16 [N][K] (transpose + cast) ----------------
__global__ __launch_bounds__(256) void transcvt_kernel(const float* __restrict__ src,
                                                       __bf16* __restrict__ dst,
                                                       int K, int N){
  __shared__ float tile[32][33];
  const int n0 = blockIdx.x*32, k0 = blockIdx.y*32;
  const int tx = threadIdx.x & 31, ty = threadIdx.x >> 5;
  #pragma unroll
  for (int i = 0; i < 32; i += 8)
    tile[ty+i][tx] = src[(size_t)(k0+ty+i)*N + n0 + tx];
  __syncthreads();
  #pragma unroll
  for (int i = 0; i < 32; i += 8)
    dst[(size_t)(n0+ty+i)*K + k0 + tx] = (__bf16)tile[tx][ty+i];
}

// ---------------- bf16 GEMM: C[M,N] = A[M,K] * Bt[N,K]^T + bias ----------------
// m97 structure; LDS-transpose epilogue -> b128 stores. 1D grid, XCD-swizzled.
// EPI 0: scatter bf16 into q/k/v [B,H,S,D];  EPI 1: fp32 C + bias.
template<int EPI, int NBX>
__global__ __launch_bounds__(256) void gemm_bt(const __bf16* __restrict__ A,
    const __bf16* __restrict__ Bt, const float* __restrict__ bias,
    __bf16* __restrict__ outb, float* __restrict__ outf, int K, int N)
{
  __shared__ union {
    struct { __bf16 a[128*32]; __bf16 b[128*32]; } s;   // 16 KB staging
    char epi[4*2304];                                    // per-wave epilogue buf
  } smg;
  const int t = threadIdx.x;
  const int lane = t & 63, w = t >> 6;
  const int wm = w >> 1, wn = w & 1;
  const int g = lane >> 4, lr = lane & 15;
  // XCD swizzle: 8 XCDs, 4 m-rows each
  const int bid = blockIdx.x;
  const int idx = bid >> 3;
  const int by = (bid & 7)*4 + idx / NBX;
  const int bx = idx % NBX;
  const int m0 = by * 128, n0 = bx * 128;
  const int srow = lane >> 2, scol = (lane & 3)*8;
  const __bf16* aS = A  + (size_t)(m0 + w*32 + srow)*K + scol;
  const __bf16* bS = Bt + (size_t)(n0 + w*32 + srow)*K + scol;
  const int ldsOff = (w*32 + srow)*32 + scol;
  f32x4 acc[4][4] = {};
  for (int k0 = 0; k0 < K; k0 += 32){
    __syncthreads();
    GLOAD_LDS16(aS + k0,          smg.s.a + ldsOff);
    GLOAD_LDS16(aS + k0 + 16*K,   smg.s.a + ldsOff + 512);
    GLOAD_LDS16(bS + k0,          smg.s.b + ldsOff);
    GLOAD_LDS16(bS + k0 + 16*K,   smg.s.b + ldsOff + 512);
    __syncthreads();
    bf16x8 af[4], bfr[4];
    #pragma unroll
    for (int i=0;i<4;i++) af[i]  = ld8(&smg.s.a[(wm*64 + i*16 + lr)*32 + g*8]);
    #pragma unroll
    for (int i=0;i<4;i++) bfr[i] = ld8(&smg.s.b[(wn*64 + i*16 + lr)*32 + g*8]);
    #pragma unroll
    for (int i=0;i<4;i++)
      #pragma unroll
      for (int j=0;j<4;j++)
        acc[i][j] = __builtin_amdgcn_mfma_f32_16x16x32_bf16(af[i], bfr[j], acc[i][j], 0,0,0);
  }
  // ---- epilogue: per-wave LDS transpose -> vector global stores ----
  __syncthreads();                       // staging reads done; reuse LDS
  float bi[4];
  #pragma unroll
  for (int j=0;j<4;j++) bi[j] = bias[n0 + wn*64 + j*16 + lr];
  char* EB = smg.epi + w*2304;           // [16 rows][144 B]
  const int orow = lane >> 2, oseg = lane & 3;
  if (EPI == 0){
    #pragma unroll
    for (int i=0;i<4;i++){
      #pragma unroll
      for (int j=0;j<4;j++)
        #pragma unroll
        for (int q=0;q<4;q++)
          *(__bf16*)(EB + (g*4+q)*144 + (j*16+lr)*2) = (__bf16)(acc[i][j][q] + bi[j]);
      #pragma unroll
      for (int rnd=0;rnd<2;rnd++){
        const int chunk = oseg + rnd*4;                  // 0..7 (8 elems each)
        bf16x8 o8 = *(const bf16x8*)(EB + orow*144 + chunk*16);
        const int gm = m0 + wm*64 + i*16 + orow;
        const int gn = n0 + wn*64 + chunk*8;
        const int b   = gm >> 11, s = gm & 2047;
        const int sec = gn >> 11, e = gn & 2047;
        const int h   = e >> 7,   d = e & 127;
        *(bf16x8*)&outb[(size_t)sec*8388608u + ((size_t)((b<<4)+h)*2048 + s)*128 + d] = o8;
      }
      __builtin_amdgcn_s_waitcnt(0);  // lgkm drain before next pass overwrite (cheap)
    }
  } else {
    #pragma unroll
    for (int i=0;i<4;i++)
      #pragma unroll
      for (int jh=0;jh<2;jh++){
        #pragma unroll
        for (int jl=0;jl<2;jl++)
          #pragma unroll
          for (int q=0;q<4;q++)
            *(float*)(EB + (g*4+q)*144 + (jl*16+lr)*4) = acc[i][jh*2+jl][q] + bi[jh*2+jl];
        #pragma unroll
        for (int rnd=0;rnd<2;rnd++){
          const int chunk = oseg + rnd*4;                // 0..7 (4 f32 each)
          f32x4 o4 = *(const f32x4*)(EB + orow*144 + chunk*16);
          const int gm = m0 + wm*64 + i*16 + orow;
          const int gn = n0 + wn*64 + jh*32 + chunk*4;
          *(f32x4*)&outf[(size_t)gm*N + gn] = o4;
        }
        __builtin_amdgcn_s_waitcnt(0);
      }
  }
}

// ---------------- flash attention: 16-q-row waves, KVBLK=32 ----------------
// grid 1024 x 256thr (4 waves). Wave owns 16 q rows (q = lane&15), full D=128.
// Swapped QK^T with PERMUTED K rows: mfma h feeds K row 8*(i>>2)+4h+(i&3) so
// lane's P covers kv = 8g+j  ->  PV B-fragment is lane-local (no shuffles).
// O^T = V^T * P^T keeps m/l/alpha per-lane (q = lane&15).
__global__ __launch_bounds__(256, 4) void attn_kernel(const __bf16* __restrict__ Q,
    const __bf16* __restrict__ Kp, const __bf16* __restrict__ Vp,
    __bf16* __restrict__ O)
{
  __shared__ union {
    struct { __bf16 k[2][32*128]; __bf16 vt[128*32]; } a;  // 16KB + 8KB
    char ot[4*4352];                                       // epilogue [16 q][272 B]
  } sm;
  char* SMB = (char*)&sm;
  const int VT0 = 16384;
  const int t = threadIdx.x, lane = t & 63, w = t >> 6;
  const int l15 = lane & 15, g = lane >> 4;
  const int bid = blockIdx.x;
  const int bh = (bid & 7)*4 + (bid >> 8);   // 4 heads per XCD -> KV L2-resident
  const int qt = (bid >> 3) & 31;
  const int q0 = qt*64 + w*16;
  const __bf16* kbase = Kp + (size_t)bh*2048*128;
  const __bf16* vbase = Vp + (size_t)bh*2048*128;

  // Q fragments (B operand): col=q=lane&15, k = g*8+j within 32-chunk kc
  const __bf16* qp = Q + ((size_t)bh*2048 + q0 + l15)*128;
  bf16x8 qf[4];
  #pragma unroll
  for (int kc = 0; kc < 4; kc++) qf[kc] = ld8(qp + kc*32 + g*8);

  // K staging: LDS linear chunk c = i*256+t; kv=c>>4, slot=c&15; src pre-swizzled
  const int skv = t >> 4, sslot = t & 15;
  const __bf16* ks0 = kbase + (size_t)skv*128 + ((sslot ^ (skv & 15))*8);
  const __bf16* ks1 = ks0 + 16*128;          // kv+16: same xor (kv&15 unchanged)
  // V: lane holds rows kv=lane&31, d = w*32 + (lane>>5)*16 + 0..15
  const int vkv = lane & 31, vhi = lane >> 5;
  const __bf16* vsrc = vbase + (size_t)vkv*128 + w*32 + vhi*16;
  // Vt write addr regs (byte, incl VT0 later): per d&3 class
  int vwB[4];
  #pragma unroll
  for (int c = 0; c < 4; c++) vwB[c] = w*2048 + vhi*1024 + ((vkv*2) ^ (c<<4));
  // K read byte offsets (within a K buffer): permuted rows
  int kaddrB[8];
  #pragma unroll
  for (int h = 0; h < 2; h++){
    const int row = 8*(l15>>2) + 4*h + (l15&3);
    #pragma unroll
    for (int kc = 0; kc < 4; kc++)
      kaddrB[h*4+kc] = row*256 + (((kc*4+g) ^ (row & 15))*16);
  }
  // Vt read base byte offset (within vt): row d0*16+l15, kv chunk g*8
  const int vrdB = l15*64 + ((g*16) ^ ((l15&3)<<4));

  f32x4 oacc[8] = {};
  float mrun = -1e30f, lrun = 0.f;
  const float C = 0.127517912f;              // (1/sqrt(128)) * log2(e)

  // prologue: stage K tile 0 into buf0; V tile 0 into regs
  GLOAD_LDS16(ks0, SMB + t*16);
  GLOAD_LDS16(ks1, SMB + 4096 + t*16);
  bf16x8 vr0 = ld8(vsrc), vr1 = ld8(vsrc + 8);

  auto tile = [&](int TT, int BUF, int NBUF){
    __syncthreads();                         // prior PV reads done; K/V(t) landed
    // write V^T (xor-swizzled, stride 64)
    #pragma unroll
    for (int e = 0; e < 8; e++)
      *(__bf16*)(SMB + VT0 + vwB[e&3] + e*64) = vr0[e];
    #pragma unroll
    for (int e = 0; e < 8; e++)
      *(__bf16*)(SMB + VT0 + vwB[e&3] + (8+e)*64) = vr1[e];
    __syncthreads();                         // Vt visible
    if (TT < 63){                            // prefetch next tile
      const size_t kvn = (size_t)(TT+1)*32;
      GLOAD_LDS16(ks0 + kvn*128, SMB + NBUF*8192 + t*16);
      GLOAD_LDS16(ks1 + kvn*128, SMB + NBUF*8192 + 4096 + t*16);
      vr0 = ld8(vsrc + kvn*128);
      vr1 = ld8(vsrc + kvn*128 + 8);
    }
    // ---- S^T: 2 mfma-halves x 4 k-chunks; lane gets kv = 8g + 4h + r ----
    f32x4 s0 = {}, s1 = {};
    #pragma unroll
    for (int kc = 0; kc < 4; kc++){
      bf16x8 k0 = *(const bf16x8*)(SMB + BUF*8192 + kaddrB[kc]);
      bf16x8 k1 = *(const bf16x8*)(SMB + BUF*8192 + kaddrB[4+kc]);
      s0 = __builtin_amdgcn_mfma_f32_16x16x32_bf16(k0, qf[kc], s0, 0,0,0);
      s1 = __builtin_amdgcn_mfma_f32_16x16x32_bf16(k1, qf[kc], s1, 0,0,0);
    }
    // ---- online softmax (q = lane&15; reduce over 4 g-groups) ----
    float pm = fmaxf(fmaxf(fmaxf(s0[0],s0[1]),fmaxf(s0[2],s0[3])),
                     fmaxf(fmaxf(s1[0],s1[1]),fmaxf(s1[2],s1[3])));
    pm = fmaxf(pm, __shfl_xor(pm, 16));
    pm = fmaxf(pm, __shfl_xor(pm, 32));
    if (!__all(pm <= mrun + 90.51f)){        // defer-max THR=8 (raw units)
      float mnew = fmaxf(mrun, pm);
      float al = exp2f((mrun - mnew)*C);
      mrun = mnew; lrun *= al;
      #pragma unroll
      for (int d = 0; d < 8; d++) oacc[d] *= al;
    }
    float pp[8];
    #pragma unroll
    for (int r = 0; r < 4; r++){
      pp[r]   = exp2f((s0[r] - mrun)*C);
      pp[4+r] = exp2f((s1[r] - mrun)*C);
    }
    float ls = ((pp[0]+pp[1])+(pp[2]+pp[3])) + ((pp[4]+pp[5])+(pp[6]+pp[7]));
    ls += __shfl_xor(ls, 16);
    ls += __shfl_xor(ls, 32);
    lrun += ls;
    // ---- pack P (lane-local!): frag elem j = kv 8g+j ----
    union { unsigned u[4]; bf16x8 v; } pw;
    pw.u[0] = cvtpk(pp[0], pp[1]);
    pw.u[1] = cvtpk(pp[2], pp[3]);
    pw.u[2] = cvtpk(pp[4], pp[5]);
    pw.u[3] = cvtpk(pp[6], pp[7]);
    // ---- O^T += V^T * P^T ----
    #pragma unroll
    for (int d0 = 0; d0 < 8; d0++){
      bf16x8 vf = *(const bf16x8*)(SMB + VT0 + vrdB + d0*1024);
      oacc[d0] = __builtin_amdgcn_mfma_f32_16x16x32_bf16(vf, pw.v, oacc[d0], 0,0,0);
    }
  };

  for (int it = 0; it < 32; ++it){
    tile(2*it,   0, 1);
    tile(2*it+1, 1, 0);
  }

  // ---- epilogue: O^T -> O via per-warp LDS transpose ----
  __syncthreads();                           // all K/Vt reads done; reuse as ot
  const float invl = 1.0f / lrun;
  #pragma unroll
  for (int d0 = 0; d0 < 8; d0++){            // lane: q=l15, d = d0*16+g*4+r
    bf16x4 o4;
    #pragma unroll
    for (int r = 0; r < 4; r++) o4[r] = (__bf16)(oacc[d0][r]*invl);
    *(bf16x4*)(SMB + w*4352 + l15*272 + d0*32 + g*8) = o4;
  }
  const int b = bh >> 4, h = bh & 15;
  const int orow = lane >> 2, oseg = lane & 3;
  #pragma unroll
  for (int itc = 0; itc < 4; itc++){
    const int chunk = oseg + itc*4;          // 16 chunks of 8 elems
    bf16x8 o8 = *(const bf16x8*)(SMB + w*4352 + orow*272 + chunk*16);
    *(bf16x8*)&O[((size_t)(b*2048 + q0 + orow))*2048 + h*128 + chunk*8] = o8;
  }
}

extern "C" void kernel_launch(void* const* d_in, const int* in_sizes, int n_in,
                              void* d_out, int out_size, void* d_ws, size_t ws_size,
                              hipStream_t stream) {
  const float* x     = (const float*)d_in[0];
  const float* Wqkv  = (const float*)d_in[1];
  const float* bqkv  = (const float*)d_in[2];
  const float* Wproj = (const float*)d_in[3];
  const float* bproj = (const float*)d_in[4];
  float* out = (float*)d_out;

  __bf16* xb     = (__bf16*)d_ws;                       // [4096][2048]
  __bf16* wqkvT  = xb     + (size_t)4096*2048;          // [6144][2048]
  __bf16* wprojT = wqkvT  + (size_t)6144*2048;          // [2048][2048]
  __bf16* qq     = wprojT + (size_t)2048*2048;          // [32][2048][128]
  __bf16* kk     = qq     + (size_t)32*2048*128;
  __bf16* vv     = kk     + (size_t)32*2048*128;
  __bf16* attb   = vv     + (size_t)32*2048*128;        // [4096][2048]

  cvt_kernel<<<2048, 256, 0, stream>>>(x, xb, (4096*2048)/4);
  transcvt_kernel<<<dim3(6144/32, 2048/32), 256, 0, stream>>>(Wqkv, wqkvT, 2048, 6144);
  transcvt_kernel<<<dim3(2048/32, 2048/32), 256, 0, stream>>>(Wproj, wprojT, 2048, 2048);
  gemm_bt<0,48><<<1536, 256, 0, stream>>>(xb, wqkvT, bqkv, qq, nullptr, 2048, 6144);
  attn_kernel<<<1024, 256, 0, stream>>>(qq, kk, vv, attb);
  gemm_bt<1,16><<<512, 256, 0, stream>>>(attb, wprojT, bproj, nullptr, out, 2048, 2048);
}